// Round 18
// baseline (84.808 us; speedup 1.0000x reference)
//
#include <hip/hip_runtime.h>
#include <hip/hip_bf16.h>
#include <stdint.h>

#define NPTS 4096
#define NNBR 16      // neighbors kept (reference keeps 17 incl. self, drops self)
#define PPB  16      // points per block
#define NSEG 32      // segments (seg = t>>4); 64 cands per half-segment
#define HALF 2048    // points staged per half
#define HSEGLEN 64   // candidates per segment per half
#define SEGPAD 68    // 68 % 32 == 4: wave's 4 seg-rows land on distinct bank-quads
#define HSTR 33      // heads stride per point (32 seg-minima + pad)
#define CAP  112     // accepted capacity (half0-tau: full-rank ~46+-7, max ~80)
#define TAUM 1.0e-3f // proxy-vs-pinned margin (bound ~4e-5; 25x safety)
#define BIGD 3.4e38f

// ---------------------------------------------------------------------------
// PINNED distance (numpy-order, no contraction) — used for the accepted-list
// d2 values so the selected neighbor set is bitwise-stable. Point coords are
// read from GLOBAL (same f32 bits as staged) so halves can be swapped freely.
// ---------------------------------------------------------------------------
__device__ __forceinline__ float sqnorm(float x, float y, float z) {
    return __fadd_rn(__fadd_rn(__fmul_rn(x, x), __fmul_rn(y, y)), __fmul_rn(z, z));
}
__device__ __forceinline__ float d2w(float px, float py, float pz, float sqp,
                                     float cx, float cy, float cz, float sqq) {
    const float dot = __fadd_rn(__fadd_rn(__fmul_rn(px, cx), __fmul_rn(py, cy)),
                                __fmul_rn(pz, cz));
    return __fsub_rn(__fadd_rn(sqp, sqq), __fadd_rn(dot, dot));
}
// CHEAP monotone proxy for the scans: e = sqq - 2*dot (= d2 - sqp up to ~ulps).
__device__ __forceinline__ float eproxy(float px, float py, float pz,
                                        float cx, float cy, float cz, float sqq) {
    const float dot = __builtin_fmaf(px, cx, __builtin_fmaf(py, cy, __fmul_rn(pz, cz)));
    return __builtin_fmaf(dot, -2.0f, sqq);
}

// generic K-deep min/max ladder over a register array (static unroll only)
#define LADK(AD, K, S)                                            \
    _Pragma("unroll")                                             \
    for (int k_ = 0; k_ < (K); ++k_) {                            \
        const float lo_ = fminf((S), AD[k_]);                     \
        (S) = fmaxf((S), AD[k_]);                                 \
        AD[k_] = lo_;                                             \
    }

// ---------------------------------------------------------------------------
// Fused exact 16-NN, half-staged, HALF0-TAU version.
// Block = 512 thr = 16 points x 32 segments, grid = 1024 (1 pt/thread).
// Distribution-free order-stat fact: rank(17th-smallest of 32 seg-minima) =
// #draws to hit 17 distinct segments ~ 23+-3.3, INDEPENDENT of segment
// length. So tau from half0's 32 seg-minima alone is a valid bound (32 real
// e-values >= 17 elems) with full-set rank ~ 2x23 ~ 46+-7 (max ~80 over 16K
// points) -> CAP 112. This removes half of scan1 and one restage entirely:
//   stage h0 -> scan1 h0 -> tau -> scan2 h0 (resident!) -> stage h1 ->
//   scan2 h1 -> rank-by-counting final.
// 192 ds_read_b128/thread (was 256), 2 stagings (was 3).
// Accepted superset still contains the true 16-NN; pinned-d2 exact final
// unchanged => identical neighbor sets. 1 pt/thread (R8/R12 spill lesson).
// ---------------------------------------------------------------------------
__global__ __launch_bounds__(512, 6) void knn_kernel(const float* __restrict__ x0,
                                                     ushort* __restrict__ nbr) {
    __shared__ float sx[NSEG * SEGPAD], sy[NSEG * SEGPAD],
                     sz[NSEG * SEGPAD], sw[NSEG * SEGPAD];   // 4 x 8,704 B
    __shared__ float2 list[PPB * CAP];                       // 14,336 B
    __shared__ float ttau[PPB];
    __shared__ int   cnt[PPB];

    float* heads = (float*)list;             // alias: dead before extraction

    const int b     = blockIdx.x >> 8;       // 256 chunks per batch
    const int chunk = blockIdx.x & 255;
    const float* Xb = x0 + b * (NPTS * 3);
    const int t = threadIdx.x;

    const int pt = t & 15, seg = t >> 4;     // seg 0..31
    const int p  = chunk * PPB + pt;         // batch-local point id
    const float px = Xb[3 * p + 0];          // own coords from GLOBAL
    const float py = Xb[3 * p + 1];          // (same f32 bits as staged)
    const float pz = Xb[3 * p + 2];
    const float sqp = sqnorm(px, py, pz);
    const int sb = seg * SEGPAD;

    // stage one 2048-point half into LDS (4 pts/thread)
#define STAGE(HB)                                                  \
    for (int i = t; i < HALF; i += 512) {                          \
        const int g = (HB) * HALF + i;                             \
        const int a = (i >> 6) * SEGPAD + (i & 63);                \
        const float x = Xb[3 * g + 0];                             \
        const float y = Xb[3 * g + 1];                             \
        const float z = Xb[3 * g + 2];                             \
        sx[a] = x; sy[a] = y; sz[a] = z; sw[a] = sqnorm(x, y, z);  \
    }

    // per-half scan2: bitmask accept + extraction with PINNED d2
#define SCAN2H(HB)                                                             \
    for (int w = 0; w < 2; ++w) {                                              \
        uint m = 0;                                                            \
        _Pragma("unroll")                                                      \
        for (int jj = 0; jj < 8; ++jj) {                                       \
            const int o = sb + w * 32 + 4 * jj;                                \
            const float4 cx4 = *(const float4*)&sx[o];                         \
            const float4 cy4 = *(const float4*)&sy[o];                         \
            const float4 cz4 = *(const float4*)&sz[o];                         \
            const float4 cw4 = *(const float4*)&sw[o];                         \
            const float s0 = eproxy(px, py, pz, cx4.x, cy4.x, cz4.x, cw4.x);   \
            const float s1 = eproxy(px, py, pz, cx4.y, cy4.y, cz4.y, cw4.y);   \
            const float s2 = eproxy(px, py, pz, cx4.z, cy4.z, cz4.z, cw4.z);   \
            const float s3 = eproxy(px, py, pz, cx4.w, cy4.w, cz4.w, cw4.w);   \
            m |= (s0 <= tv) ? (1u << (4 * jj + 0)) : 0u;                       \
            m |= (s1 <= tv) ? (1u << (4 * jj + 1)) : 0u;                       \
            m |= (s2 <= tv) ? (1u << (4 * jj + 2)) : 0u;                       \
            m |= (s3 <= tv) ? (1u << (4 * jj + 3)) : 0u;                       \
        }                                                                      \
        while (m) {                                                            \
            const int bpos = __ffs(m) - 1;                                     \
            m &= m - 1;                                                        \
            const int l = seg * HSEGLEN + w * 32 + bpos;                       \
            const int q = (HB) * HALF + l;   /* batch-local cand id */         \
            if (q != p) {                                                      \
                const int qa = (l >> 6) * SEGPAD + (l & 63);                   \
                const float d2 = d2w(px, py, pz, sqp,                          \
                                     sx[qa], sy[qa], sz[qa], sw[qa]);          \
                const int o2 = atomicAdd(&cnt[pt], 1);                         \
                if (o2 < CAP) list[pt * CAP + o2] = make_float2(d2, __int_as_float(q)); \
            }                                                                  \
        }                                                                      \
    }

    // ---- phase A: stage half0, scan1 on it (dual min-chains) ----
    STAGE(0)
    if (t < PPB) cnt[t] = 0;
    __syncthreads();

    float ha = BIGD, hb = BIGD;
    for (int j = 0; j < 16; j += 2) {
        const int oa = sb + 4 * j;
        const int ob = oa + 4;
        const float4 cxa = *(const float4*)&sx[oa];
        const float4 cya = *(const float4*)&sy[oa];
        const float4 cza = *(const float4*)&sz[oa];
        const float4 cwa = *(const float4*)&sw[oa];
        const float4 cxb = *(const float4*)&sx[ob];
        const float4 cyb = *(const float4*)&sy[ob];
        const float4 czb = *(const float4*)&sz[ob];
        const float4 cwb = *(const float4*)&sw[ob];
        const float sa0 = eproxy(px, py, pz, cxa.x, cya.x, cza.x, cwa.x);
        const float sa1 = eproxy(px, py, pz, cxa.y, cya.y, cza.y, cwa.y);
        const float sa2 = eproxy(px, py, pz, cxa.z, cya.z, cza.z, cwa.z);
        const float sa3 = eproxy(px, py, pz, cxa.w, cya.w, cza.w, cwa.w);
        const float sb0 = eproxy(px, py, pz, cxb.x, cyb.x, czb.x, cwb.x);
        const float sb1 = eproxy(px, py, pz, cxb.y, cyb.y, czb.y, cwb.y);
        const float sb2 = eproxy(px, py, pz, cxb.z, cyb.z, czb.z, cwb.z);
        const float sb3 = eproxy(px, py, pz, cxb.w, cyb.w, czb.w, cwb.w);
        ha = fminf(ha, fminf(fminf(sa0, sa1), fminf(sa2, sa3)));
        hb = fminf(hb, fminf(fminf(sb0, sb1), fminf(sb2, sb3)));
    }
    heads[pt * HSTR + seg] = fminf(ha, hb);  // this half0-segment's minimum
    __syncthreads();

    // ---- tau: 1 thr/pt, LAD17 over the 32 half0 seg-minima ----
    if (t < PPB) {
        float ad[17];
#pragma unroll
        for (int k = 0; k < 17; ++k) ad[k] = BIGD;
        const float* src = heads + t * HSTR;
        for (int e = 0; e < 32; ++e) {
            float s = src[(e + t) & 31];
            LADK(ad, 17, s)
        }
        ttau[t] = ad[16];                    // 17th-smallest seg-minimum
    }
    __syncthreads();                         // heads dead; list reuses the space

    // ---- phase B: scan2 on the still-resident half0 ----
    const float tv = ttau[pt] + TAUM;
    SCAN2H(0)
    __syncthreads();                         // everyone done reading half0

    // ---- phase C: stage half1, scan2 on it ----
    STAGE(1)
    __syncthreads();
    SCAN2H(1)
    __syncthreads();

    // ---- final: rank-by-counting, all 512 threads (32 slots x 16 points) ----
    {
        const int p2 = t >> 5;               // point 0..15
        const int sl = t & 31;               // slot 0..31
        const int n  = min(cnt[p2], CAP);
        const uint base = (uint)(b * NPTS + chunk * PPB + p2) * (uint)NNBR;
        for (int e = sl; e < n; e += 32) {
            const float2 ve = list[p2 * CAP + e];
            const int ie = __float_as_int(ve.y);
            int r = 0;
            for (int f = 0; f < n; ++f) {
                const float2 vf = list[p2 * CAP + f];
                const bool lt = (vf.x < ve.x) ||
                                (vf.x == ve.x && __float_as_int(vf.y) < ie);
                r += lt ? 1 : 0;
            }
            if (r < NNBR) nbr[base + r] = (ushort)ie;
        }
    }
#undef STAGE
#undef SCAN2H
}

// ---------------------------------------------------------------------------
// MLP + neighbor mean (one wave per point, lane = output channel) with the
// v0 passthrough copy folded in (first 48 blocks copy one float4/thread).
// ---------------------------------------------------------------------------
__global__ __launch_bounds__(256) void mlp_kernel(const float* __restrict__ x0,
                                                  const float* __restrict__ v0,
                                                  const float* __restrict__ W,
                                                  const float* __restrict__ bias,
                                                  const ushort* __restrict__ nbr,
                                                  float* __restrict__ out) {
    const int t   = threadIdx.x;
    const int gid = blockIdx.x * 256 + t;
    if (gid < (4 * NPTS * 3) / 4) {                 // 12288 float4 copies
        ((float4*)(out + 4 * NPTS * 64))[gid] = ((const float4*)v0)[gid];
    }

    const int wave = t >> 6;
    const int lane = t & 63;
    const int gp   = blockIdx.x * 4 + wave;         // global point id 0..16383
    const int b    = gp >> 12;
    const int p    = gp & (NPTS - 1);

    const float* Xb = x0 + b * (NPTS * 3);
    const float* Vb = v0 + b * (NPTS * 3);

    float w[12];
#pragma unroll
    for (int k = 0; k < 12; ++k) w[k] = W[k * 64 + lane];
    const float bb = bias[lane];

    const float xi0 = Xb[p * 3 + 0], xi1 = Xb[p * 3 + 1], xi2 = Xb[p * 3 + 2];
    const float vi0 = Vb[p * 3 + 0], vi1 = Vb[p * 3 + 1], vi2 = Vb[p * 3 + 2];

    const float base = bb + w[0] * xi0 + w[1] * xi1 + w[2] * xi2
                          + w[6] * vi0 + w[7] * vi1 + w[8] * vi2;

    __shared__ float nb[4][NNBR][8];
    if (lane < NNBR) {
        const int j = (int)nbr[(uint)gp * NNBR + lane];
        nb[wave][lane][0] = Xb[j * 3 + 0];
        nb[wave][lane][1] = Xb[j * 3 + 1];
        nb[wave][lane][2] = Xb[j * 3 + 2];
        nb[wave][lane][3] = Vb[j * 3 + 0];
        nb[wave][lane][4] = Vb[j * 3 + 1];
        nb[wave][lane][5] = Vb[j * 3 + 2];
    }
    __syncthreads();

    float acc = 0.0f;
#pragma unroll
    for (int n = 0; n < NNBR; ++n) {
        const float h = base + w[3]  * nb[wave][n][0] + w[4]  * nb[wave][n][1]
                             + w[5]  * nb[wave][n][2] + w[9]  * nb[wave][n][3]
                             + w[10] * nb[wave][n][4] + w[11] * nb[wave][n][5];
        acc += fmaxf(h, 0.0f);
    }

    out[(size_t)gp * 64 + lane] = acc * (1.0f / 16.0f);
}

extern "C" void kernel_launch(void* const* d_in, const int* in_sizes, int n_in,
                              void* d_out, int out_size, void* d_ws, size_t ws_size,
                              hipStream_t stream) {
    const float* x0 = (const float*)d_in[0];   // (4, 12288)
    const float* v0 = (const float*)d_in[1];   // (4, 12288)
    const float* W  = (const float*)d_in[2];   // (12, 64)
    const float* bb = (const float*)d_in[3];   // (64,)
    float* out = (float*)d_out;

    ushort* nbr = (ushort*)d_ws;               // 16384 * 16 * 2B = 512 KB

    // 1) fused exact 16-NN: 1024 blocks (4 batches x 256 chunks of 16 points),
    //    512 threads (16 pts x 32 segs), half-staged, half0-tau.
    knn_kernel<<<1024, 512, 0, stream>>>(x0, nbr);

    // 2) MLP + mean (+ folded v0 copy): 4 points/block, 4096 blocks.
    mlp_kernel<<<4096, 256, 0, stream>>>(x0, v0, W, bb, nbr, out);
}

// Round 19
// 55.954 us; speedup vs baseline: 1.5157x; 1.5157x over previous
//
#include <hip/hip_runtime.h>
#include <hip/hip_bf16.h>
#include <stdint.h>

#define NPTS 4096
#define NNBR 16      // neighbors kept (reference keeps 17 incl. self, drops self)
#define PPB  16      // points per block
#define NSEG 32      // segments (seg = t>>4); 64 cands per half-segment
#define HALF 2048    // points staged per half
#define HSEGLEN 64   // candidates per segment per half
#define SEGPAD 68    // 68 % 32 == 4: wave's 4 seg-rows land on distinct bank-quads
#define HSTR 33      // heads stride per point (32 seg-minima + pad)
#define CAP  96      // accepted capacity (full-statistic tau: rank ~23, proven R16/R17)
#define TAUM 1.0e-3f // proxy-vs-pinned margin (bound ~5e-5; 20x safety)
#define BIGD 3.4e38f

// ---------------------------------------------------------------------------
// PINNED distance (numpy-order, no contraction) — used ONLY in extraction so
// the accepted-list d2 values (and thus the selected 16-NN sets) are bitwise
// stable. sqq is recomputed with the PINNED sqnorm from staged coords — the
// exact bits the old sw array held.
// ---------------------------------------------------------------------------
__device__ __forceinline__ float sqnorm(float x, float y, float z) {
    return __fadd_rn(__fadd_rn(__fmul_rn(x, x), __fmul_rn(y, y)), __fmul_rn(z, z));
}
__device__ __forceinline__ float d2r(float px, float py, float pz, float sqp,
                                     float cx, float cy, float cz) {
    const float sqq = sqnorm(cx, cy, cz);
    const float dot = __fadd_rn(__fadd_rn(__fmul_rn(px, cx), __fmul_rn(py, cy)),
                                __fmul_rn(pz, cz));
    return __fsub_rn(__fadd_rn(sqp, sqq), __fadd_rn(dot, dot));
}
// CHEAP proxy for the scans: e = sqq - 2*dot, sqq recomputed in-register
// (7 VALU). ONE macro for scan1 AND scan2 -> identical bits per candidate;
// TAUM absorbs proxy-vs-pinned rounding at the acceptance boundary.
__device__ __forceinline__ float eproxy2(float px, float py, float pz,
                                         float cx, float cy, float cz) {
    const float sqq = __builtin_fmaf(cz, cz, __builtin_fmaf(cy, cy, __fmul_rn(cx, cx)));
    const float dot = __builtin_fmaf(px, cx, __builtin_fmaf(py, cy, __fmul_rn(pz, cz)));
    return __builtin_fmaf(dot, -2.0f, sqq);
}

// generic K-deep min/max ladder over a register array (static unroll only)
#define LADK(AD, K, S)                                            \
    _Pragma("unroll")                                             \
    for (int k_ = 0; k_ < (K); ++k_) {                            \
        const float lo_ = fminf((S), AD[k_]);                     \
        (S) = fmaxf((S), AD[k_]);                                 \
        AD[k_] = lo_;                                             \
    }

// ---------------------------------------------------------------------------
// Fused exact 16-NN, half-staged, NO-SW version (4 blocks/CU).
// Block = 512 thr = 16 points x 32 segments, grid = 1024 (1 pt/thread).
// Exactly R17's proven structure and tau statistic (seg-minima over BOTH
// halves -> rank(tau) ~ 23; R18 showed a looser tau quadruples tail work),
// with the sw array dropped: sqq recomputed in-register (+3 VALU/eval, VALU
// has slack since scan1 is min-only) for 3 reads/quad instead of 4 (192
// ds_read_b128/thread vs 256) AND LDS 47.5 -> 38.5 KB -> 4 blocks/CU (full
// 2048-thread occupancy; was 3 blocks). R10's earlier no-sw regression came
// from simultaneously loosening tau + no occupancy gain — both fixed here.
// Extraction recomputes PINNED sqnorm => pinned d2 bits unchanged => the
// rank-by-counting final emits identical neighbor sets to R16/R17.
// 1 pt/thread (R8/R12 spill lesson).
// ---------------------------------------------------------------------------
__global__ __launch_bounds__(512, 8) void knn_kernel(const float* __restrict__ x0,
                                                     ushort* __restrict__ nbr) {
    __shared__ float sx[NSEG * SEGPAD], sy[NSEG * SEGPAD],
                     sz[NSEG * SEGPAD];                      // 3 x 8,704 B
    __shared__ float2 list[PPB * CAP];                       // 12,288 B
    __shared__ float ttau[PPB];
    __shared__ int   cnt[PPB];

    float* heads = (float*)list;             // alias: dead before extraction

    const int b     = blockIdx.x >> 8;       // 256 chunks per batch
    const int chunk = blockIdx.x & 255;
    const float* Xb = x0 + b * (NPTS * 3);
    const int t = threadIdx.x;

    const int pt = t & 15, seg = t >> 4;     // seg 0..31
    const int p  = chunk * PPB + pt;         // batch-local point id
    const float px = Xb[3 * p + 0];          // own coords from GLOBAL
    const float py = Xb[3 * p + 1];          // (same f32 bits as staged)
    const float pz = Xb[3 * p + 2];
    const float sqp = sqnorm(px, py, pz);
    const int sb = seg * SEGPAD;

    // stage one 2048-point half into LDS (4 pts/thread, 3 arrays)
#define STAGE(HB)                                                  \
    for (int i = t; i < HALF; i += 512) {                          \
        const int g = (HB) * HALF + i;                             \
        const int a = (i >> 6) * SEGPAD + (i & 63);                \
        sx[a] = Xb[3 * g + 0];                                     \
        sy[a] = Xb[3 * g + 1];                                     \
        sz[a] = Xb[3 * g + 2];                                     \
    }

    // per-half min-chain over this thread's 64 candidates (dual chains)
#define SCAN1H(HA, HBCH)                                           \
    for (int j = 0; j < 16; j += 2) {                              \
        const int oa = sb + 4 * j;                                 \
        const int ob = oa + 4;                                     \
        const float4 cxa = *(const float4*)&sx[oa];                \
        const float4 cya = *(const float4*)&sy[oa];                \
        const float4 cza = *(const float4*)&sz[oa];                \
        const float4 cxb = *(const float4*)&sx[ob];                \
        const float4 cyb = *(const float4*)&sy[ob];                \
        const float4 czb = *(const float4*)&sz[ob];                \
        const float sa0 = eproxy2(px, py, pz, cxa.x, cya.x, cza.x); \
        const float sa1 = eproxy2(px, py, pz, cxa.y, cya.y, cza.y); \
        const float sa2 = eproxy2(px, py, pz, cxa.z, cya.z, cza.z); \
        const float sa3 = eproxy2(px, py, pz, cxa.w, cya.w, cza.w); \
        const float sb0 = eproxy2(px, py, pz, cxb.x, cyb.x, czb.x); \
        const float sb1 = eproxy2(px, py, pz, cxb.y, cyb.y, czb.y); \
        const float sb2 = eproxy2(px, py, pz, cxb.z, cyb.z, czb.z); \
        const float sb3 = eproxy2(px, py, pz, cxb.w, cyb.w, czb.w); \
        HA   = fminf(HA,   fminf(fminf(sa0, sa1), fminf(sa2, sa3))); \
        HBCH = fminf(HBCH, fminf(fminf(sb0, sb1), fminf(sb2, sb3))); \
    }

    // per-half scan2: bitmask accept + extraction with PINNED d2
#define SCAN2H(HB)                                                             \
    for (int w = 0; w < 2; ++w) {                                              \
        uint m = 0;                                                            \
        _Pragma("unroll")                                                      \
        for (int jj = 0; jj < 8; ++jj) {                                       \
            const int o = sb + w * 32 + 4 * jj;                                \
            const float4 cx4 = *(const float4*)&sx[o];                         \
            const float4 cy4 = *(const float4*)&sy[o];                         \
            const float4 cz4 = *(const float4*)&sz[o];                         \
            const float s0 = eproxy2(px, py, pz, cx4.x, cy4.x, cz4.x);         \
            const float s1 = eproxy2(px, py, pz, cx4.y, cy4.y, cz4.y);         \
            const float s2 = eproxy2(px, py, pz, cx4.z, cy4.z, cz4.z);         \
            const float s3 = eproxy2(px, py, pz, cx4.w, cy4.w, cz4.w);         \
            m |= (s0 <= tv) ? (1u << (4 * jj + 0)) : 0u;                       \
            m |= (s1 <= tv) ? (1u << (4 * jj + 1)) : 0u;                       \
            m |= (s2 <= tv) ? (1u << (4 * jj + 2)) : 0u;                       \
            m |= (s3 <= tv) ? (1u << (4 * jj + 3)) : 0u;                       \
        }                                                                      \
        while (m) {                                                            \
            const int bpos = __ffs(m) - 1;                                     \
            m &= m - 1;                                                        \
            const int l = seg * HSEGLEN + w * 32 + bpos;                       \
            const int q = (HB) * HALF + l;   /* batch-local cand id */         \
            if (q != p) {                                                      \
                const int qa = (l >> 6) * SEGPAD + (l & 63);                   \
                const float d2 = d2r(px, py, pz, sqp, sx[qa], sy[qa], sz[qa]); \
                const int o2 = atomicAdd(&cnt[pt], 1);                         \
                if (o2 < CAP) list[pt * CAP + o2] = make_float2(d2, __int_as_float(q)); \
            }                                                                  \
        }                                                                      \
    }

    // ---- phase A: stage half0, scan1 on it ----
    STAGE(0)
    if (t < PPB) cnt[t] = 0;
    __syncthreads();

    float ha = BIGD, hb = BIGD;
    SCAN1H(ha, hb)
    __syncthreads();                         // done reading half0

    // ---- phase B: stage half1, finish scan1, write seg-minima ----
    STAGE(1)
    __syncthreads();
    SCAN1H(ha, hb)
    heads[pt * HSTR + seg] = fminf(ha, hb);  // min over all 128 cands
    __syncthreads();

    // ---- tau: 1 thr/pt, LAD17 over the 32 seg-minima (rotated reads) ----
    if (t < PPB) {
        float ad[17];
#pragma unroll
        for (int k = 0; k < 17; ++k) ad[k] = BIGD;
        const float* src = heads + t * HSTR;
        for (int e = 0; e < 32; ++e) {
            float s = src[(e + t) & 31];
            LADK(ad, 17, s)
        }
        ttau[t] = ad[16];                    // 17th-smallest seg-minimum
    }
    __syncthreads();                         // heads dead; list reuses the space

    // ---- phase C: scan2 on resident half1, then restage half0 and scan2 ----
    const float tv = ttau[pt] + TAUM;
    SCAN2H(1)
    __syncthreads();                         // done reading half1
    STAGE(0)
    __syncthreads();
    SCAN2H(0)
    __syncthreads();

    // ---- final: rank-by-counting, all 512 threads (32 slots x 16 points) ----
    {
        const int p2 = t >> 5;               // point 0..15
        const int sl = t & 31;               // slot 0..31
        const int n  = min(cnt[p2], CAP);
        const uint base = (uint)(b * NPTS + chunk * PPB + p2) * (uint)NNBR;
        for (int e = sl; e < n; e += 32) {
            const float2 ve = list[p2 * CAP + e];
            const int ie = __float_as_int(ve.y);
            int r = 0;
            for (int f = 0; f < n; ++f) {
                const float2 vf = list[p2 * CAP + f];
                const bool lt = (vf.x < ve.x) ||
                                (vf.x == ve.x && __float_as_int(vf.y) < ie);
                r += lt ? 1 : 0;
            }
            if (r < NNBR) nbr[base + r] = (ushort)ie;
        }
    }
#undef STAGE
#undef SCAN1H
#undef SCAN2H
}

// ---------------------------------------------------------------------------
// MLP + neighbor mean (one wave per point, lane = output channel) with the
// v0 passthrough copy folded in (first 48 blocks copy one float4/thread).
// ---------------------------------------------------------------------------
__global__ __launch_bounds__(256) void mlp_kernel(const float* __restrict__ x0,
                                                  const float* __restrict__ v0,
                                                  const float* __restrict__ W,
                                                  const float* __restrict__ bias,
                                                  const ushort* __restrict__ nbr,
                                                  float* __restrict__ out) {
    const int t   = threadIdx.x;
    const int gid = blockIdx.x * 256 + t;
    if (gid < (4 * NPTS * 3) / 4) {                 // 12288 float4 copies
        ((float4*)(out + 4 * NPTS * 64))[gid] = ((const float4*)v0)[gid];
    }

    const int wave = t >> 6;
    const int lane = t & 63;
    const int gp   = blockIdx.x * 4 + wave;         // global point id 0..16383
    const int b    = gp >> 12;
    const int p    = gp & (NPTS - 1);

    const float* Xb = x0 + b * (NPTS * 3);
    const float* Vb = v0 + b * (NPTS * 3);

    float w[12];
#pragma unroll
    for (int k = 0; k < 12; ++k) w[k] = W[k * 64 + lane];
    const float bb = bias[lane];

    const float xi0 = Xb[p * 3 + 0], xi1 = Xb[p * 3 + 1], xi2 = Xb[p * 3 + 2];
    const float vi0 = Vb[p * 3 + 0], vi1 = Vb[p * 3 + 1], vi2 = Vb[p * 3 + 2];

    const float base = bb + w[0] * xi0 + w[1] * xi1 + w[2] * xi2
                          + w[6] * vi0 + w[7] * vi1 + w[8] * vi2;

    __shared__ float nb[4][NNBR][8];
    if (lane < NNBR) {
        const int j = (int)nbr[(uint)gp * NNBR + lane];
        nb[wave][lane][0] = Xb[j * 3 + 0];
        nb[wave][lane][1] = Xb[j * 3 + 1];
        nb[wave][lane][2] = Xb[j * 3 + 2];
        nb[wave][lane][3] = Vb[j * 3 + 0];
        nb[wave][lane][4] = Vb[j * 3 + 1];
        nb[wave][lane][5] = Vb[j * 3 + 2];
    }
    __syncthreads();

    float acc = 0.0f;
#pragma unroll
    for (int n = 0; n < NNBR; ++n) {
        const float h = base + w[3]  * nb[wave][n][0] + w[4]  * nb[wave][n][1]
                             + w[5]  * nb[wave][n][2] + w[9]  * nb[wave][n][3]
                             + w[10] * nb[wave][n][4] + w[11] * nb[wave][n][5];
        acc += fmaxf(h, 0.0f);
    }

    out[(size_t)gp * 64 + lane] = acc * (1.0f / 16.0f);
}

extern "C" void kernel_launch(void* const* d_in, const int* in_sizes, int n_in,
                              void* d_out, int out_size, void* d_ws, size_t ws_size,
                              hipStream_t stream) {
    const float* x0 = (const float*)d_in[0];   // (4, 12288)
    const float* v0 = (const float*)d_in[1];   // (4, 12288)
    const float* W  = (const float*)d_in[2];   // (12, 64)
    const float* bb = (const float*)d_in[3];   // (64,)
    float* out = (float*)d_out;

    ushort* nbr = (ushort*)d_ws;               // 16384 * 16 * 2B = 512 KB

    // 1) fused exact 16-NN: 1024 blocks (4 batches x 256 chunks of 16 points),
    //    512 threads (16 pts x 32 segs), half-staged, no-sw, 4 blocks/CU.
    knn_kernel<<<1024, 512, 0, stream>>>(x0, nbr);

    // 2) MLP + mean (+ folded v0 copy): 4 points/block, 4096 blocks.
    mlp_kernel<<<4096, 256, 0, stream>>>(x0, v0, W, bb, nbr, out);
}

// Round 20
// 55.826 us; speedup vs baseline: 1.5192x; 1.0023x over previous
//
#include <hip/hip_runtime.h>
#include <hip/hip_bf16.h>
#include <stdint.h>

#define NPTS 4096
#define NNBR 16      // neighbors kept (reference keeps 17 incl. self, drops self)
#define PPB  16      // points per block
#define NSEG 32      // segments (seg = t>>4); 64 cands per half-segment
#define HALF 2048    // points staged per half
#define HSEGLEN 64   // candidates per segment per half
#define SEGPAD 68    // 68 % 32 == 4: wave's 4 seg-rows land on distinct bank-quads
#define HSTR 33      // heads stride per point (32 seg-minima + pad)
#define CAP  96      // accepted capacity (full-statistic tau: rank ~23, proven)
#define TAUM 1.0e-3f // proxy-vs-pinned margin (bound ~5e-5; 20x safety)
#define BIGD 3.4e38f

// ---------------------------------------------------------------------------
// PINNED distance (numpy-order, no contraction) — extraction only; bitwise
// stable accepted-list d2 => stable 16-NN sets.
// ---------------------------------------------------------------------------
__device__ __forceinline__ float sqnorm(float x, float y, float z) {
    return __fadd_rn(__fadd_rn(__fmul_rn(x, x), __fmul_rn(y, y)), __fmul_rn(z, z));
}
__device__ __forceinline__ float d2r(float px, float py, float pz, float sqp,
                                     float cx, float cy, float cz) {
    const float sqq = sqnorm(cx, cy, cz);
    const float dot = __fadd_rn(__fadd_rn(__fmul_rn(px, cx), __fmul_rn(py, cy)),
                                __fmul_rn(pz, cz));
    return __fsub_rn(__fadd_rn(sqp, sqq), __fadd_rn(dot, dot));
}
// CHEAP proxy for the scans (7 VALU, sqq in-register). One macro for both
// scans -> identical bits per candidate; TAUM covers proxy-vs-pinned delta.
__device__ __forceinline__ float eproxy2(float px, float py, float pz,
                                         float cx, float cy, float cz) {
    const float sqq = __builtin_fmaf(cz, cz, __builtin_fmaf(cy, cy, __fmul_rn(cx, cx)));
    const float dot = __builtin_fmaf(px, cx, __builtin_fmaf(py, cy, __fmul_rn(pz, cz)));
    return __builtin_fmaf(dot, -2.0f, sqq);
}

// generic K-deep min/max ladder over a register array (static unroll only)
#define LADK(AD, K, S)                                            \
    _Pragma("unroll")                                             \
    for (int k_ = 0; k_ < (K); ++k_) {                            \
        const float lo_ = fminf((S), AD[k_]);                     \
        (S) = fmaxf((S), AD[k_]);                                 \
        AD[k_] = lo_;                                             \
    }

// ---------------------------------------------------------------------------
// Fused exact 16-NN, half-staged, no-sw, 4 blocks/CU (R19 = 53.5us proven)
// + T14 ASYNC-STAGE SPLIT: the two later stagings issue their 12 global
// loads into NAMED REGISTERS before the preceding scan phase (global reads
// touch no LDS -> legal across the barrier structure); after the barrier
// that retires reads of the old half, only the ds_writes remain. HBM/L2
// latency hides under ~15us of scan compute instead of sitting exposed
// between barriers. LDS contents at every program point are bit-identical
// to R19 => identical neighbor sets (scheduling-only change).
// 1 pt/thread (R8/R12 spill lesson); 12 named regs (rule: no dyn-indexed
// arrays). Spill sentinel: WRITE_SIZE.
// ---------------------------------------------------------------------------
__global__ __launch_bounds__(512, 8) void knn_kernel(const float* __restrict__ x0,
                                                     ushort* __restrict__ nbr) {
    __shared__ float sx[NSEG * SEGPAD], sy[NSEG * SEGPAD],
                     sz[NSEG * SEGPAD];                      // 3 x 8,704 B
    __shared__ float2 list[PPB * CAP];                       // 12,288 B
    __shared__ float ttau[PPB];
    __shared__ int   cnt[PPB];

    float* heads = (float*)list;             // alias: dead before extraction

    const int b     = blockIdx.x >> 8;       // 256 chunks per batch
    const int chunk = blockIdx.x & 255;
    const float* Xb = x0 + b * (NPTS * 3);
    const int t = threadIdx.x;

    const int pt = t & 15, seg = t >> 4;     // seg 0..31
    const int p  = chunk * PPB + pt;         // batch-local point id
    const float px = Xb[3 * p + 0];          // own coords from GLOBAL
    const float py = Xb[3 * p + 1];          // (same f32 bits as staged)
    const float pz = Xb[3 * p + 2];
    const float sqp = sqnorm(px, py, pz);
    const int sb = seg * SEGPAD;

    // 12 named staging registers (4 points x 3 coords per thread)
    float r0, r1, r2, r3, r4, r5, r6, r7, r8, r9, r10, r11;

    // issue the 12 global loads for half HB (no LDS access)
#define LOADR(HB) {                                                \
        const int g0 = 3 * ((HB) * HALF + t);                      \
        r0 = Xb[g0 + 0];    r1  = Xb[g0 + 1];    r2  = Xb[g0 + 2]; \
        r3 = Xb[g0 + 1536]; r4  = Xb[g0 + 1537]; r5  = Xb[g0 + 1538]; \
        r6 = Xb[g0 + 3072]; r7  = Xb[g0 + 3073]; r8  = Xb[g0 + 3074]; \
        r9 = Xb[g0 + 4608]; r10 = Xb[g0 + 4609]; r11 = Xb[g0 + 4610]; }

    // write the 12 registers to the staging layout (same addrs as STAGE)
#define WRITER() {                                                 \
        const int a0 = (t >> 6) * SEGPAD + (t & 63);               \
        sx[a0] = r0; sy[a0] = r1; sz[a0] = r2;                     \
        const int a1 = a0 + 8  * SEGPAD;                           \
        sx[a1] = r3; sy[a1] = r4; sz[a1] = r5;                     \
        const int a2 = a0 + 16 * SEGPAD;                           \
        sx[a2] = r6; sy[a2] = r7; sz[a2] = r8;                     \
        const int a3 = a0 + 24 * SEGPAD;                           \
        sx[a3] = r9; sy[a3] = r10; sz[a3] = r11; }

    // per-half min-chain over this thread's 64 candidates (dual chains)
#define SCAN1H(HA, HBCH)                                           \
    for (int j = 0; j < 16; j += 2) {                              \
        const int oa = sb + 4 * j;                                 \
        const int ob = oa + 4;                                     \
        const float4 cxa = *(const float4*)&sx[oa];                \
        const float4 cya = *(const float4*)&sy[oa];                \
        const float4 cza = *(const float4*)&sz[oa];                \
        const float4 cxb = *(const float4*)&sx[ob];                \
        const float4 cyb = *(const float4*)&sy[ob];                \
        const float4 czb = *(const float4*)&sz[ob];                \
        const float sa0 = eproxy2(px, py, pz, cxa.x, cya.x, cza.x); \
        const float sa1 = eproxy2(px, py, pz, cxa.y, cya.y, cza.y); \
        const float sa2 = eproxy2(px, py, pz, cxa.z, cya.z, cza.z); \
        const float sa3 = eproxy2(px, py, pz, cxa.w, cya.w, cza.w); \
        const float sb0 = eproxy2(px, py, pz, cxb.x, cyb.x, czb.x); \
        const float sb1 = eproxy2(px, py, pz, cxb.y, cyb.y, czb.y); \
        const float sb2 = eproxy2(px, py, pz, cxb.z, cyb.z, czb.z); \
        const float sb3 = eproxy2(px, py, pz, cxb.w, cyb.w, czb.w); \
        HA   = fminf(HA,   fminf(fminf(sa0, sa1), fminf(sa2, sa3))); \
        HBCH = fminf(HBCH, fminf(fminf(sb0, sb1), fminf(sb2, sb3))); \
    }

    // per-half scan2: bitmask accept + extraction with PINNED d2
#define SCAN2H(HB)                                                             \
    for (int w = 0; w < 2; ++w) {                                              \
        uint m = 0;                                                            \
        _Pragma("unroll")                                                      \
        for (int jj = 0; jj < 8; ++jj) {                                       \
            const int o = sb + w * 32 + 4 * jj;                                \
            const float4 cx4 = *(const float4*)&sx[o];                         \
            const float4 cy4 = *(const float4*)&sy[o];                         \
            const float4 cz4 = *(const float4*)&sz[o];                         \
            const float s0 = eproxy2(px, py, pz, cx4.x, cy4.x, cz4.x);         \
            const float s1 = eproxy2(px, py, pz, cx4.y, cy4.y, cz4.y);         \
            const float s2 = eproxy2(px, py, pz, cx4.z, cy4.z, cz4.z);         \
            const float s3 = eproxy2(px, py, pz, cx4.w, cy4.w, cz4.w);         \
            m |= (s0 <= tv) ? (1u << (4 * jj + 0)) : 0u;                       \
            m |= (s1 <= tv) ? (1u << (4 * jj + 1)) : 0u;                       \
            m |= (s2 <= tv) ? (1u << (4 * jj + 2)) : 0u;                       \
            m |= (s3 <= tv) ? (1u << (4 * jj + 3)) : 0u;                       \
        }                                                                      \
        while (m) {                                                            \
            const int bpos = __ffs(m) - 1;                                     \
            m &= m - 1;                                                        \
            const int l = seg * HSEGLEN + w * 32 + bpos;                       \
            const int q = (HB) * HALF + l;   /* batch-local cand id */         \
            if (q != p) {                                                      \
                const int qa = (l >> 6) * SEGPAD + (l & 63);                   \
                const float d2 = d2r(px, py, pz, sqp, sx[qa], sy[qa], sz[qa]); \
                const int o2 = atomicAdd(&cnt[pt], 1);                         \
                if (o2 < CAP) list[pt * CAP + o2] = make_float2(d2, __int_as_float(q)); \
            }                                                                  \
        }                                                                      \
    }

    // ---- phase A: stage half0 (direct), then scan1 h0 with h1-loads in flight
    {
        const int g0 = 3 * t;
        const int a0 = (t >> 6) * SEGPAD + (t & 63);
        sx[a0] = Xb[g0 + 0];    sy[a0] = Xb[g0 + 1];    sz[a0] = Xb[g0 + 2];
        const int a1 = a0 + 8 * SEGPAD;
        sx[a1] = Xb[g0 + 1536]; sy[a1] = Xb[g0 + 1537]; sz[a1] = Xb[g0 + 1538];
        const int a2 = a0 + 16 * SEGPAD;
        sx[a2] = Xb[g0 + 3072]; sy[a2] = Xb[g0 + 3073]; sz[a2] = Xb[g0 + 3074];
        const int a3 = a0 + 24 * SEGPAD;
        sx[a3] = Xb[g0 + 4608]; sy[a3] = Xb[g0 + 4609]; sz[a3] = Xb[g0 + 4610];
    }
    if (t < PPB) cnt[t] = 0;
    __syncthreads();

    LOADR(1)                                 // half1 loads issued EARLY
    float ha = BIGD, hb = BIGD;
    SCAN1H(ha, hb)                           // scan h0 hides the load latency
    __syncthreads();                         // all done READING half0

    // ---- phase B: write half1 from regs, finish scan1, write seg-minima ----
    WRITER()
    __syncthreads();
    SCAN1H(ha, hb)
    heads[pt * HSTR + seg] = fminf(ha, hb);  // min over all 128 cands
    __syncthreads();

    // ---- tau: 1 thr/pt, LAD17 over the 32 seg-minima (rotated reads) ----
    if (t < PPB) {
        float ad[17];
#pragma unroll
        for (int k = 0; k < 17; ++k) ad[k] = BIGD;
        const float* src = heads + t * HSTR;
        for (int e = 0; e < 32; ++e) {
            float s = src[(e + t) & 31];
            LADK(ad, 17, s)
        }
        ttau[t] = ad[16];                    // 17th-smallest seg-minimum
    }
    __syncthreads();                         // heads dead; list reuses the space

    // ---- phase C: scan2 h1 (resident) with h0-reloads in flight ----
    const float tv = ttau[pt] + TAUM;
    LOADR(0)                                 // restage loads issued EARLY (L2-hot)
    SCAN2H(1)
    __syncthreads();                         // done reading half1
    WRITER()
    __syncthreads();
    SCAN2H(0)
    __syncthreads();

    // ---- final: rank-by-counting, all 512 threads (32 slots x 16 points) ----
    {
        const int p2 = t >> 5;               // point 0..15
        const int sl = t & 31;               // slot 0..31
        const int n  = min(cnt[p2], CAP);
        const uint base = (uint)(b * NPTS + chunk * PPB + p2) * (uint)NNBR;
        for (int e = sl; e < n; e += 32) {
            const float2 ve = list[p2 * CAP + e];
            const int ie = __float_as_int(ve.y);
            int r = 0;
            for (int f = 0; f < n; ++f) {
                const float2 vf = list[p2 * CAP + f];
                const bool lt = (vf.x < ve.x) ||
                                (vf.x == ve.x && __float_as_int(vf.y) < ie);
                r += lt ? 1 : 0;
            }
            if (r < NNBR) nbr[base + r] = (ushort)ie;
        }
    }
#undef LOADR
#undef WRITER
#undef SCAN1H
#undef SCAN2H
}

// ---------------------------------------------------------------------------
// MLP + neighbor mean (one wave per point, lane = output channel) with the
// v0 passthrough copy folded in (first 48 blocks copy one float4/thread).
// ---------------------------------------------------------------------------
__global__ __launch_bounds__(256) void mlp_kernel(const float* __restrict__ x0,
                                                  const float* __restrict__ v0,
                                                  const float* __restrict__ W,
                                                  const float* __restrict__ bias,
                                                  const ushort* __restrict__ nbr,
                                                  float* __restrict__ out) {
    const int t   = threadIdx.x;
    const int gid = blockIdx.x * 256 + t;
    if (gid < (4 * NPTS * 3) / 4) {                 // 12288 float4 copies
        ((float4*)(out + 4 * NPTS * 64))[gid] = ((const float4*)v0)[gid];
    }

    const int wave = t >> 6;
    const int lane = t & 63;
    const int gp   = blockIdx.x * 4 + wave;         // global point id 0..16383
    const int b    = gp >> 12;
    const int p    = gp & (NPTS - 1);

    const float* Xb = x0 + b * (NPTS * 3);
    const float* Vb = v0 + b * (NPTS * 3);

    float w[12];
#pragma unroll
    for (int k = 0; k < 12; ++k) w[k] = W[k * 64 + lane];
    const float bb = bias[lane];

    const float xi0 = Xb[p * 3 + 0], xi1 = Xb[p * 3 + 1], xi2 = Xb[p * 3 + 2];
    const float vi0 = Vb[p * 3 + 0], vi1 = Vb[p * 3 + 1], vi2 = Vb[p * 3 + 2];

    const float base = bb + w[0] * xi0 + w[1] * xi1 + w[2] * xi2
                          + w[6] * vi0 + w[7] * vi1 + w[8] * vi2;

    __shared__ float nb[4][NNBR][8];
    if (lane < NNBR) {
        const int j = (int)nbr[(uint)gp * NNBR + lane];
        nb[wave][lane][0] = Xb[j * 3 + 0];
        nb[wave][lane][1] = Xb[j * 3 + 1];
        nb[wave][lane][2] = Xb[j * 3 + 2];
        nb[wave][lane][3] = Vb[j * 3 + 0];
        nb[wave][lane][4] = Vb[j * 3 + 1];
        nb[wave][lane][5] = Vb[j * 3 + 2];
    }
    __syncthreads();

    float acc = 0.0f;
#pragma unroll
    for (int n = 0; n < NNBR; ++n) {
        const float h = base + w[3]  * nb[wave][n][0] + w[4]  * nb[wave][n][1]
                             + w[5]  * nb[wave][n][2] + w[9]  * nb[wave][n][3]
                             + w[10] * nb[wave][n][4] + w[11] * nb[wave][n][5];
        acc += fmaxf(h, 0.0f);
    }

    out[(size_t)gp * 64 + lane] = acc * (1.0f / 16.0f);
}

extern "C" void kernel_launch(void* const* d_in, const int* in_sizes, int n_in,
                              void* d_out, int out_size, void* d_ws, size_t ws_size,
                              hipStream_t stream) {
    const float* x0 = (const float*)d_in[0];   // (4, 12288)
    const float* v0 = (const float*)d_in[1];   // (4, 12288)
    const float* W  = (const float*)d_in[2];   // (12, 64)
    const float* bb = (const float*)d_in[3];   // (64,)
    float* out = (float*)d_out;

    ushort* nbr = (ushort*)d_ws;               // 16384 * 16 * 2B = 512 KB

    // 1) fused exact 16-NN: 1024 blocks (4 batches x 256 chunks of 16 points),
    //    512 threads, half-staged, no-sw, async-stage split, 4 blocks/CU.
    knn_kernel<<<1024, 512, 0, stream>>>(x0, nbr);

    // 2) MLP + mean (+ folded v0 copy): 4 points/block, 4096 blocks.
    mlp_kernel<<<4096, 256, 0, stream>>>(x0, v0, W, bb, nbr, out);
}

// Round 21
// 53.027 us; speedup vs baseline: 1.5993x; 1.0528x over previous
//
#include <hip/hip_runtime.h>
#include <hip/hip_bf16.h>
#include <stdint.h>

#define NPTS 4096
#define NNBR 16      // neighbors kept (reference keeps 17 incl. self, drops self)
#define PPB  16      // points per block
#define NSEG 32      // segments (seg = t>>4); 64 cands per half-segment
#define HALF 2048    // points staged per half
#define HSEGLEN 64   // candidates per segment per half
#define SEGPAD 68    // 68 % 32 == 4: wave's 4 seg-rows land on distinct bank-quads
#define HSTR 33      // heads stride per point (32 seg-minima + pad)
#define CAP  96      // accepted capacity (full-statistic tau: rank ~23, proven)
#define TAUM 1.0e-3f // proxy-vs-pinned margin (bound ~5e-5; 20x safety)
#define BIGD 3.4e38f

// ---------------------------------------------------------------------------
// PINNED distance (numpy-order, no contraction) — extraction only; bitwise
// stable accepted-list d2 => stable 16-NN sets.
// ---------------------------------------------------------------------------
__device__ __forceinline__ float sqnorm(float x, float y, float z) {
    return __fadd_rn(__fadd_rn(__fmul_rn(x, x), __fmul_rn(y, y)), __fmul_rn(z, z));
}
__device__ __forceinline__ float d2r(float px, float py, float pz, float sqp,
                                     float cx, float cy, float cz) {
    const float sqq = sqnorm(cx, cy, cz);
    const float dot = __fadd_rn(__fadd_rn(__fmul_rn(px, cx), __fmul_rn(py, cy)),
                                __fmul_rn(pz, cz));
    return __fsub_rn(__fadd_rn(sqp, sqq), __fadd_rn(dot, dot));
}
// CHEAP proxy for the scans (7 VALU, sqq in-register). One macro for both
// scans -> identical bits per candidate; TAUM covers proxy-vs-pinned delta.
__device__ __forceinline__ float eproxy2(float px, float py, float pz,
                                         float cx, float cy, float cz) {
    const float sqq = __builtin_fmaf(cz, cz, __builtin_fmaf(cy, cy, __fmul_rn(cx, cx)));
    const float dot = __builtin_fmaf(px, cx, __builtin_fmaf(py, cy, __fmul_rn(pz, cz)));
    return __builtin_fmaf(dot, -2.0f, sqq);
}

// generic K-deep min/max ladder over a register array (static unroll only)
#define LADK(AD, K, S)                                            \
    _Pragma("unroll")                                             \
    for (int k_ = 0; k_ < (K); ++k_) {                            \
        const float lo_ = fminf((S), AD[k_]);                     \
        (S) = fmaxf((S), AD[k_]);                                 \
        AD[k_] = lo_;                                             \
    }

// ---------------------------------------------------------------------------
// FULLY FUSED: exact 16-NN + per-edge MLP + neighbor mean + v0 copy.
// Block = 512 thr = 16 points x 32 segments, grid = 1024 (1 pt/thread).
// kNN part identical to R19/R20 (proven 53.5us, absmax 0.0546875):
//   half-staged (4 blocks/CU), min-only scan1, full-statistic tau (rank~23),
//   bitmask scan2 + pinned-d2 extraction, rank-by-counting select.
// NEW: rank writes go to LDS nbrL[16][16] (every rank 0..15 hit exactly once
// since accepted>=16); after a barrier the block stages its 256 neighbors'
// Xj/Vj into the dead list region and runs the mlp math VERBATIM
// (8 pts x 64 ch x 2 iters), writing out directly. v0 copy folds into the
// first 24 blocks. One dispatch total — no nbr round-trip through HBM.
// ---------------------------------------------------------------------------
__global__ __launch_bounds__(512, 8) void fused_kernel(const float* __restrict__ x0,
                                                       const float* __restrict__ v0,
                                                       const float* __restrict__ W,
                                                       const float* __restrict__ bias,
                                                       float* __restrict__ out) {
    __shared__ float sx[NSEG * SEGPAD], sy[NSEG * SEGPAD],
                     sz[NSEG * SEGPAD];                      // 3 x 8,704 B
    __shared__ float2 list[PPB * CAP];                       // 12,288 B
    __shared__ ushort nbrL[PPB][NNBR];                       // 512 B
    __shared__ float ttau[PPB];
    __shared__ int   cnt[PPB];

    float* heads = (float*)list;             // alias: dead before extraction
    float* nbf   = (float*)list;             // alias: dead after rank phase

    const int b     = blockIdx.x >> 8;       // 256 chunks per batch
    const int chunk = blockIdx.x & 255;
    const float* Xb = x0 + b * (NPTS * 3);
    const float* Vb = v0 + b * (NPTS * 3);
    const int t = threadIdx.x;

    // ---- folded v0 passthrough: first 24 blocks copy one float4/thread ----
    {
        const int gid = blockIdx.x * 512 + t;
        if (gid < (4 * NPTS * 3) / 4)
            ((float4*)(out + 4 * NPTS * 64))[gid] = ((const float4*)v0)[gid];
    }

    const int pt = t & 15, seg = t >> 4;     // seg 0..31
    const int p  = chunk * PPB + pt;         // batch-local point id
    const float px = Xb[3 * p + 0];          // own coords from GLOBAL
    const float py = Xb[3 * p + 1];          // (same f32 bits as staged)
    const float pz = Xb[3 * p + 2];
    const float sqp = sqnorm(px, py, pz);
    const int sb = seg * SEGPAD;

    // stage one 2048-point half into LDS (4 pts/thread, 3 arrays)
#define STAGE(HB)                                                  \
    for (int i = t; i < HALF; i += 512) {                          \
        const int g = (HB) * HALF + i;                             \
        const int a = (i >> 6) * SEGPAD + (i & 63);                \
        sx[a] = Xb[3 * g + 0];                                     \
        sy[a] = Xb[3 * g + 1];                                     \
        sz[a] = Xb[3 * g + 2];                                     \
    }

    // per-half min-chain over this thread's 64 candidates (dual chains)
#define SCAN1H(HA, HBCH)                                           \
    for (int j = 0; j < 16; j += 2) {                              \
        const int oa = sb + 4 * j;                                 \
        const int ob = oa + 4;                                     \
        const float4 cxa = *(const float4*)&sx[oa];                \
        const float4 cya = *(const float4*)&sy[oa];                \
        const float4 cza = *(const float4*)&sz[oa];                \
        const float4 cxb = *(const float4*)&sx[ob];                \
        const float4 cyb = *(const float4*)&sy[ob];                \
        const float4 czb = *(const float4*)&sz[ob];                \
        const float sa0 = eproxy2(px, py, pz, cxa.x, cya.x, cza.x); \
        const float sa1 = eproxy2(px, py, pz, cxa.y, cya.y, cza.y); \
        const float sa2 = eproxy2(px, py, pz, cxa.z, cya.z, cza.z); \
        const float sa3 = eproxy2(px, py, pz, cxa.w, cya.w, cza.w); \
        const float sb0 = eproxy2(px, py, pz, cxb.x, cyb.x, czb.x); \
        const float sb1 = eproxy2(px, py, pz, cxb.y, cyb.y, czb.y); \
        const float sb2 = eproxy2(px, py, pz, cxb.z, cyb.z, czb.z); \
        const float sb3 = eproxy2(px, py, pz, cxb.w, cyb.w, czb.w); \
        HA   = fminf(HA,   fminf(fminf(sa0, sa1), fminf(sa2, sa3))); \
        HBCH = fminf(HBCH, fminf(fminf(sb0, sb1), fminf(sb2, sb3))); \
    }

    // per-half scan2: bitmask accept + extraction with PINNED d2
#define SCAN2H(HB)                                                             \
    for (int w = 0; w < 2; ++w) {                                              \
        uint m = 0;                                                            \
        _Pragma("unroll")                                                      \
        for (int jj = 0; jj < 8; ++jj) {                                       \
            const int o = sb + w * 32 + 4 * jj;                                \
            const float4 cx4 = *(const float4*)&sx[o];                         \
            const float4 cy4 = *(const float4*)&sy[o];                         \
            const float4 cz4 = *(const float4*)&sz[o];                         \
            const float s0 = eproxy2(px, py, pz, cx4.x, cy4.x, cz4.x);         \
            const float s1 = eproxy2(px, py, pz, cx4.y, cy4.y, cz4.y);         \
            const float s2 = eproxy2(px, py, pz, cx4.z, cy4.z, cz4.z);         \
            const float s3 = eproxy2(px, py, pz, cx4.w, cy4.w, cz4.w);         \
            m |= (s0 <= tv) ? (1u << (4 * jj + 0)) : 0u;                       \
            m |= (s1 <= tv) ? (1u << (4 * jj + 1)) : 0u;                       \
            m |= (s2 <= tv) ? (1u << (4 * jj + 2)) : 0u;                       \
            m |= (s3 <= tv) ? (1u << (4 * jj + 3)) : 0u;                       \
        }                                                                      \
        while (m) {                                                            \
            const int bpos = __ffs(m) - 1;                                     \
            m &= m - 1;                                                        \
            const int l = seg * HSEGLEN + w * 32 + bpos;                       \
            const int q = (HB) * HALF + l;   /* batch-local cand id */         \
            if (q != p) {                                                      \
                const int qa = (l >> 6) * SEGPAD + (l & 63);                   \
                const float d2 = d2r(px, py, pz, sqp, sx[qa], sy[qa], sz[qa]); \
                const int o2 = atomicAdd(&cnt[pt], 1);                         \
                if (o2 < CAP) list[pt * CAP + o2] = make_float2(d2, __int_as_float(q)); \
            }                                                                  \
        }                                                                      \
    }

    // ---- phase A: stage half0, scan1 on it ----
    STAGE(0)
    if (t < PPB) cnt[t] = 0;
    __syncthreads();

    float ha = BIGD, hb = BIGD;
    SCAN1H(ha, hb)
    __syncthreads();                         // done reading half0

    // ---- phase B: stage half1, finish scan1, write seg-minima ----
    STAGE(1)
    __syncthreads();
    SCAN1H(ha, hb)
    heads[pt * HSTR + seg] = fminf(ha, hb);  // min over all 128 cands
    __syncthreads();

    // ---- tau: 1 thr/pt, LAD17 over the 32 seg-minima (rotated reads) ----
    if (t < PPB) {
        float ad[17];
#pragma unroll
        for (int k = 0; k < 17; ++k) ad[k] = BIGD;
        const float* src = heads + t * HSTR;
        for (int e = 0; e < 32; ++e) {
            float s = src[(e + t) & 31];
            LADK(ad, 17, s)
        }
        ttau[t] = ad[16];                    // 17th-smallest seg-minimum
    }
    __syncthreads();                         // heads dead; list reuses the space

    // ---- phase C: scan2 on resident half1, then restage half0 and scan2 ----
    const float tv = ttau[pt] + TAUM;
    SCAN2H(1)
    __syncthreads();                         // done reading half1
    STAGE(0)
    __syncthreads();
    SCAN2H(0)
    __syncthreads();

    // ---- rank-by-counting select -> LDS neighbor table (ranks 0..15) ----
    {
        const int p2 = t >> 5;               // point 0..15
        const int sl = t & 31;               // slot 0..31
        const int n  = min(cnt[p2], CAP);    // always >= 16 (tau >= e_(17))
        for (int e = sl; e < n; e += 32) {
            const float2 ve = list[p2 * CAP + e];
            const int ie = __float_as_int(ve.y);
            int r = 0;
            for (int f = 0; f < n; ++f) {
                const float2 vf = list[p2 * CAP + f];
                const bool lt = (vf.x < ve.x) ||
                                (vf.x == ve.x && __float_as_int(vf.y) < ie);
                r += lt ? 1 : 0;
            }
            if (r < NNBR) nbrL[p2][r] = (ushort)ie;
        }
    }
    __syncthreads();                         // list dead; nbf reuses the space

    // ---- fused MLP stage: 256 threads gather neighbor Xj/Vj (6 floats) ----
    if (t < 256) {
        const int p2 = t >> 4, nn = t & 15;
        const int j  = (int)nbrL[p2][nn];
        float* dst = nbf + (p2 * NNBR + nn) * 6;
        dst[0] = Xb[3 * j + 0];
        dst[1] = Xb[3 * j + 1];
        dst[2] = Xb[3 * j + 2];
        dst[3] = Vb[3 * j + 0];
        dst[4] = Vb[3 * j + 1];
        dst[5] = Vb[3 * j + 2];
    }
    __syncthreads();

    // ---- fused MLP compute: 8 waves x 64 channels, 2 points per wave ----
    {
        const int lane = t & 63;
        const int wv   = t >> 6;             // 0..7
        float w[12];
#pragma unroll
        for (int k = 0; k < 12; ++k) w[k] = W[k * 64 + lane];
        const float bb = bias[lane];

#pragma unroll
        for (int pp = 0; pp < 2; ++pp) {
            const int pi = wv + 8 * pp;      // point 0..15
            const int pg = chunk * PPB + pi; // batch-local point id
            const float xi0 = Xb[pg * 3 + 0], xi1 = Xb[pg * 3 + 1], xi2 = Xb[pg * 3 + 2];
            const float vi0 = Vb[pg * 3 + 0], vi1 = Vb[pg * 3 + 1], vi2 = Vb[pg * 3 + 2];
            const float base = bb + w[0] * xi0 + w[1] * xi1 + w[2] * xi2
                                  + w[6] * vi0 + w[7] * vi1 + w[8] * vi2;
            float acc = 0.0f;
#pragma unroll
            for (int n = 0; n < NNBR; ++n) {
                const float* f = nbf + (pi * NNBR + n) * 6;
                const float h = base + w[3]  * f[0] + w[4]  * f[1]
                                     + w[5]  * f[2] + w[9]  * f[3]
                                     + w[10] * f[4] + w[11] * f[5];
                acc += fmaxf(h, 0.0f);
            }
            out[(size_t)(b * NPTS + pg) * 64 + lane] = acc * (1.0f / 16.0f);
        }
    }
#undef STAGE
#undef SCAN1H
#undef SCAN2H
}

extern "C" void kernel_launch(void* const* d_in, const int* in_sizes, int n_in,
                              void* d_out, int out_size, void* d_ws, size_t ws_size,
                              hipStream_t stream) {
    const float* x0 = (const float*)d_in[0];   // (4, 12288)
    const float* v0 = (const float*)d_in[1];   // (4, 12288)
    const float* W  = (const float*)d_in[2];   // (12, 64)
    const float* bb = (const float*)d_in[3];   // (64,)
    float* out = (float*)d_out;

    // Single fused dispatch: 16-NN + MLP + mean + v0 copy.
    // 1024 blocks (4 batches x 256 chunks of 16 points), 512 threads.
    fused_kernel<<<1024, 512, 0, stream>>>(x0, v0, W, bb, out);
}